// Round 1
// baseline (685.780 us; speedup 1.0000x reference)
//
#include <hip/hip_runtime.h>
#include <hip/hip_bf16.h>

#define INF_F (__builtin_inff())

// ---------------------------------------------------------------------------
// Problem constants: B=4, N=16384, S=4096, D1=128, D2=256, MLP=(256,128)
// M = B*N = 65536 flattened points.
// ---------------------------------------------------------------------------

// points2 [B][256][4096] -> p2t [B][4096][256] (row per source point, for
// coalesced 1KB gather rows in interp)
__global__ __launch_bounds__(256) void transpose_k(const float* __restrict__ in,
                                                   float* __restrict__ out) {
  __shared__ float tile[32][33];
  int b = blockIdx.z;
  int s0 = blockIdx.x * 32;
  int k0 = blockIdx.y * 32;
  int tx = threadIdx.x, ty = threadIdx.y;  // 32 x 8
  const float* src = in + ((size_t)b * 256 + k0) * 4096 + s0;
  for (int r = ty; r < 32; r += 8) tile[r][tx] = src[(size_t)r * 4096 + tx];
  __syncthreads();
  float* dst = out + ((size_t)b * 4096 + s0) * 256 + k0;
  for (int r = ty; r < 32; r += 8) dst[(size_t)r * 256 + tx] = tile[tx][r];
}

__device__ __forceinline__ void top3_insert(float d, int s, float& e0, float& e1,
                                            float& e2, int& j0, int& j1, int& j2) {
  if (d < e2) {
    if (d < e1) {
      e2 = e1; j2 = j1;
      if (d < e0) { e1 = e0; j1 = j0; e0 = d; j0 = s; }
      else        { e1 = d;  j1 = s; }
    } else { e2 = d; j2 = s; }
  }
}

// 3-NN + inverse-distance weights. 512 blocks x 256 thr; block = 128 query
// points of one batch; 2 threads/query (S halves), merged via LDS.
__global__ __launch_bounds__(256) void knn_k(const float* __restrict__ xyz1,
                                             const float* __restrict__ xyz2,
                                             const int* __restrict__ idx1,
                                             const int* __restrict__ idx2,
                                             int* __restrict__ idx3,
                                             float* __restrict__ wgt) {
  __shared__ float4 sP[4096];  // x,y,z,|p|^2  (64KB)
  __shared__ int sId[4096];    // 16KB
  int bid = blockIdx.x;
  int b = bid >> 7;
  int n0 = (bid & 127) * 128;
  int t = threadIdx.x;
  for (int s = t; s < 4096; s += 256) {
    float x = xyz2[(b * 3 + 0) * 4096 + s];
    float y = xyz2[(b * 3 + 1) * 4096 + s];
    float z = xyz2[(b * 3 + 2) * 4096 + s];
    sP[s] = make_float4(x, y, z, fmaf(x, x, fmaf(y, y, z * z)));
    sId[s] = idx2[b * 4096 + s];
  }
  __syncthreads();
  int nl = t & 127, half = t >> 7;
  int n = n0 + nl;
  float px = xyz1[(b * 3 + 0) * 16384 + n];
  float py = xyz1[(b * 3 + 1) * 16384 + n];
  float pz = xyz1[(b * 3 + 2) * 16384 + n];
  int myid = idx1[b * 16384 + n];
  float pn = fmaf(px, px, fmaf(py, py, pz * pz));
  float e0 = INF_F, e1 = INF_F, e2 = INF_F;
  int j0 = 0, j1 = 0, j2 = 0;
  int sBeg = half * 2048, sEnd = sBeg + 2048;
#pragma unroll 4
  for (int s = sBeg; s < sEnd; ++s) {
    float4 p = sP[s];  // LDS broadcast (all lanes same addr) - conflict-free
    float dot = fmaf(px, p.x, fmaf(py, p.y, pz * p.z));
    float d = fmaf(-2.f, dot, pn + p.w);  // matches ref formula |a|^2+|b|^2-2ab
    d = (sId[s] == myid) ? d : INF_F;
    top3_insert(d, s, e0, e1, e2, j0, j1, j2);
  }
  __syncthreads();
  float* sf = (float*)sP;
  int* si = (int*)sP;
  sf[t * 8 + 0] = e0; sf[t * 8 + 1] = e1; sf[t * 8 + 2] = e2;
  si[t * 8 + 3] = j0; si[t * 8 + 4] = j1; si[t * 8 + 5] = j2;
  __syncthreads();
  if (t < 128) {
    int pb = (t + 128) * 8;  // partner covers s >= 2048 (higher idx: strict <
                             // keeps top_k's lowest-index tie order)
    for (int q = 0; q < 3; ++q)
      top3_insert(sf[pb + q], si[pb + 3 + q], e0, e1, e2, j0, j1, j2);
    float r0 = 1.f / (e0 + 1e-8f);
    float r1 = 1.f / (e1 + 1e-8f);
    float r2 = 1.f / (e2 + 1e-8f);
    float rs = r0 + r1 + r2;
    float w0 = r0 / rs, w1 = r1 / rs, w2 = r2 / rs;
    if (e0 > 1e8f) w0 = 0.f;   // ref: where(d3 > BIG, 0, w) + nan_to_num
    if (e1 > 1e8f) w1 = 0.f;
    if (e2 > 1e8f) w2 = 0.f;
    size_t i = (size_t)b * 16384 + n;
    idx3[i * 3 + 0] = j0; idx3[i * 3 + 1] = j1; idx3[i * 3 + 2] = j2;
    wgt[i * 3 + 0] = w0;  wgt[i * 3 + 1] = w1;  wgt[i * 3 + 2] = w2;
  }
}

// interp[i][k] = sum_j w_j * p2t[b][id_j][k]   (i-major rows of 256 floats)
__global__ __launch_bounds__(256) void interp_k(const float* __restrict__ p2t,
                                                const int* __restrict__ idx3,
                                                const float* __restrict__ wgt,
                                                float* __restrict__ itp) {
  int i0 = blockIdx.x * 128;  // 512 blocks
  int b = i0 >> 14;
  int k = threadIdx.x;
  const float* base = p2t + (size_t)b * 4096 * 256;
#pragma unroll 2
  for (int ii = 0; ii < 128; ++ii) {
    int i = i0 + ii;
    int id0 = idx3[i * 3 + 0], id1 = idx3[i * 3 + 1], id2 = idx3[i * 3 + 2];
    float w0 = wgt[i * 3 + 0], w1v = wgt[i * 3 + 1], w2v = wgt[i * 3 + 2];
    float v = w0 * base[id0 * 256 + k];
    v = fmaf(w1v, base[id1 * 256 + k], v);
    v = fmaf(w2v, base[id2 * 256 + k], v);
    itp[(size_t)i * 256 + k] = v;
  }
}

// GEMM1: h1[c][i] = sum_k w1[c][k] * A[k][i], A = [points1 ; interp], K=384.
// (bias b1 omitted: exactly cancelled by BN mean subtraction)
// 64x64 tile, 4x4 micro, K-chunk 16. grid (1024, 4).
__global__ __launch_bounds__(256) void gemm1_k(const float* __restrict__ p1,
                                               const float* __restrict__ itp,
                                               const float* __restrict__ w1,
                                               float* __restrict__ h1) {
  __shared__ float sW[16][68];  // [kk][cc], pad 68 keeps b128 align, <=2-way banks
  __shared__ float sA[16][68];  // [kk][ii]
  int t = threadIdx.x;
  int i0 = blockIdx.x * 64;
  int c0 = blockIdx.y * 64;
  int b = i0 >> 14;
  int n0 = i0 & 16383;
  int tc = t >> 4, ti = t & 15;
  float acc[4][4] = {{0.f, 0.f, 0.f, 0.f}, {0.f, 0.f, 0.f, 0.f},
                     {0.f, 0.f, 0.f, 0.f}, {0.f, 0.f, 0.f, 0.f}};
  int w_cc = t >> 2, w_k4 = (t & 3) * 4;
  int aA_kk = t >> 4, aA_i4 = (t & 15) * 4;  // k-major source (points1)
  int aB_ii = t >> 2, aB_k4 = (t & 3) * 4;   // i-major source (interp)
  for (int kc = 0; kc < 24; ++kc) {
    int k0 = kc * 16;
    __syncthreads();
    {
      float4 wv = *(const float4*)&w1[(size_t)(c0 + w_cc) * 384 + k0 + w_k4];
      sW[w_k4 + 0][w_cc] = wv.x; sW[w_k4 + 1][w_cc] = wv.y;
      sW[w_k4 + 2][w_cc] = wv.z; sW[w_k4 + 3][w_cc] = wv.w;
    }
    if (k0 < 128) {
      float4 av = *(const float4*)&p1[((size_t)(b * 128 + k0 + aA_kk)) * 16384 + n0 + aA_i4];
      *(float4*)&sA[aA_kk][aA_i4] = av;
    } else {
      float4 av = *(const float4*)&itp[((size_t)(i0 + aB_ii)) * 256 + (k0 - 128) + aB_k4];
      sA[aB_k4 + 0][aB_ii] = av.x; sA[aB_k4 + 1][aB_ii] = av.y;
      sA[aB_k4 + 2][aB_ii] = av.z; sA[aB_k4 + 3][aB_ii] = av.w;
    }
    __syncthreads();
#pragma unroll
    for (int kk = 0; kk < 16; ++kk) {
      float av4[4], wv4[4];
      *(float4*)av4 = *(const float4*)&sA[kk][ti * 4];
      *(float4*)wv4 = *(const float4*)&sW[kk][tc * 4];
#pragma unroll
      for (int a = 0; a < 4; ++a)
#pragma unroll
        for (int q = 0; q < 4; ++q)
          acc[a][q] = fmaf(wv4[a], av4[q], acc[a][q]);
    }
  }
#pragma unroll
  for (int j = 0; j < 4; ++j) {
    int c = c0 + tc * 4 + j;
    float4 o = make_float4(acc[j][0], acc[j][1], acc[j][2], acc[j][3]);
    *(float4*)&h1[(size_t)c * 65536 + i0 + ti * 4] = o;
  }
}

// per-channel BN stats -> fold to a*x + c.  MODE 0: src [C][65536] rows.
// MODE 1: src is d_out [B][128][16384], channel c at 4 strided chunks.
template <int MODE>
__global__ __launch_bounds__(256) void bnstats_k(const float* __restrict__ src,
                                                 const float* __restrict__ gamma,
                                                 const float* __restrict__ beta,
                                                 float* __restrict__ A,
                                                 float* __restrict__ Cc) {
  int c = blockIdx.x;
  int t = threadIdx.x;
  float s1 = 0.f, s2 = 0.f;
  if (MODE == 0) {
    const float* p = src + (size_t)c * 65536;
    for (int e = t * 4; e < 65536; e += 1024) {
      float4 v = *(const float4*)&p[e];
      s1 += (v.x + v.y) + (v.z + v.w);
      s2 += fmaf(v.x, v.x, v.y * v.y) + fmaf(v.z, v.z, v.w * v.w);
    }
  } else {
    for (int bb = 0; bb < 4; ++bb) {
      const float* p = src + ((size_t)(bb * 128 + c)) * 16384;
      for (int e = t * 4; e < 16384; e += 1024) {
        float4 v = *(const float4*)&p[e];
        s1 += (v.x + v.y) + (v.z + v.w);
        s2 += fmaf(v.x, v.x, v.y * v.y) + fmaf(v.z, v.z, v.w * v.w);
      }
    }
  }
  __shared__ float r1[256], r2[256];
  r1[t] = s1; r2[t] = s2;
  __syncthreads();
  for (int off = 128; off > 0; off >>= 1) {
    if (t < off) { r1[t] += r1[t + off]; r2[t] += r2[t + off]; }
    __syncthreads();
  }
  if (t == 0) {
    float mean = r1[0] * (1.f / 65536.f);
    float var = r2[0] * (1.f / 65536.f) - mean * mean;  // biased, as torch BN
    float a = gamma[c] * rsqrtf(var + 1e-5f);
    A[c] = a;
    Cc[c] = beta[c] - mean * a;
  }
}

// GEMM2: out[b][o][n] = sum_c w2[o][c] * relu(a1[c]*h1[c][i]+c1[c]); grid (1024,2)
__global__ __launch_bounds__(256) void gemm2_k(const float* __restrict__ h1,
                                               const float* __restrict__ w2,
                                               const float* __restrict__ a1,
                                               const float* __restrict__ c1,
                                               float* __restrict__ out) {
  __shared__ float sW[16][68];
  __shared__ float sA[16][68];
  int t = threadIdx.x;
  int i0 = blockIdx.x * 64;
  int o0 = blockIdx.y * 64;
  int b = i0 >> 14;
  int n0 = i0 & 16383;
  int tc = t >> 4, ti = t & 15;
  float acc[4][4] = {{0.f, 0.f, 0.f, 0.f}, {0.f, 0.f, 0.f, 0.f},
                     {0.f, 0.f, 0.f, 0.f}, {0.f, 0.f, 0.f, 0.f}};
  int w_cc = t >> 2, w_k4 = (t & 3) * 4;
  int aA_kk = t >> 4, aA_i4 = (t & 15) * 4;
  for (int kc = 0; kc < 16; ++kc) {
    int k0 = kc * 16;
    __syncthreads();
    {
      float4 wv = *(const float4*)&w2[(size_t)(o0 + w_cc) * 256 + k0 + w_k4];
      sW[w_k4 + 0][w_cc] = wv.x; sW[w_k4 + 1][w_cc] = wv.y;
      sW[w_k4 + 2][w_cc] = wv.z; sW[w_k4 + 3][w_cc] = wv.w;
    }
    {
      int c = k0 + aA_kk;
      float sc = a1[c], sh = c1[c];
      float4 hv = *(const float4*)&h1[(size_t)c * 65536 + i0 + aA_i4];
      float4 av;
      av.x = fmaxf(fmaf(sc, hv.x, sh), 0.f);
      av.y = fmaxf(fmaf(sc, hv.y, sh), 0.f);
      av.z = fmaxf(fmaf(sc, hv.z, sh), 0.f);
      av.w = fmaxf(fmaf(sc, hv.w, sh), 0.f);
      *(float4*)&sA[aA_kk][aA_i4] = av;
    }
    __syncthreads();
#pragma unroll
    for (int kk = 0; kk < 16; ++kk) {
      float av4[4], wv4[4];
      *(float4*)av4 = *(const float4*)&sA[kk][ti * 4];
      *(float4*)wv4 = *(const float4*)&sW[kk][tc * 4];
#pragma unroll
      for (int a = 0; a < 4; ++a)
#pragma unroll
        for (int q = 0; q < 4; ++q)
          acc[a][q] = fmaf(wv4[a], av4[q], acc[a][q]);
    }
  }
#pragma unroll
  for (int j = 0; j < 4; ++j) {
    int o = o0 + tc * 4 + j;
    float4 v = make_float4(acc[j][0], acc[j][1], acc[j][2], acc[j][3]);
    *(float4*)&out[((size_t)(b * 128 + o)) * 16384 + n0 + ti * 4] = v;
  }
}

// final in-place BN2 + relu on d_out
__global__ __launch_bounds__(256) void bnapply_k(float* __restrict__ out,
                                                 const float* __restrict__ A,
                                                 const float* __restrict__ Cc) {
  int e4 = blockIdx.x * 256 + threadIdx.x;  // 8192 blocks * 256 = 2M float4s
  int elem = e4 * 4;
  int o = (elem >> 14) & 127;
  float a = A[o], cc = Cc[o];
  float4 v = ((float4*)out)[e4];
  v.x = fmaxf(fmaf(a, v.x, cc), 0.f);
  v.y = fmaxf(fmaf(a, v.y, cc), 0.f);
  v.z = fmaxf(fmaf(a, v.z, cc), 0.f);
  v.w = fmaxf(fmaf(a, v.w, cc), 0.f);
  ((float4*)out)[e4] = v;
}

extern "C" void kernel_launch(void* const* d_in, const int* in_sizes, int n_in,
                              void* d_out, int out_size, void* d_ws, size_t ws_size,
                              hipStream_t stream) {
  const float* xyz1 = (const float*)d_in[0];
  const float* xyz2 = (const float*)d_in[1];
  const float* p1   = (const float*)d_in[2];
  const float* p2   = (const float*)d_in[3];
  const int*   idx1 = (const int*)d_in[4];
  const int*   idx2 = (const int*)d_in[5];
  const float* w1   = (const float*)d_in[6];
  // d_in[7] = b1, d_in[11] = b2: exactly absorbed by BN mean subtraction
  const float* g1   = (const float*)d_in[8];
  const float* be1  = (const float*)d_in[9];
  const float* w2   = (const float*)d_in[10];
  const float* g2   = (const float*)d_in[12];
  const float* be2  = (const float*)d_in[13];
  float* out = (float*)d_out;

  char* ws = (char*)d_ws;
  // layout: idx3 0.75MB | wgt 0.75MB | h1 64MB (p2t 16.8MB aliased: dead
  // before gemm1 writes) | interp 64MB | folded BN params 4KB  => ~135.7MB
  int*   idx3 = (int*)(ws + 0x0);
  float* wgt  = (float*)(ws + 0xC0000);
  float* h1   = (float*)(ws + 0x180000);
  float* p2t  = (float*)(ws + 0x180000);
  float* itp  = (float*)(ws + 0x180000 + 0x4000000);
  float* a1   = (float*)(ws + 0x180000 + 0x8000000);
  float* c1   = a1 + 256;
  float* a2   = c1 + 256;
  float* c2   = a2 + 128;

  hipLaunchKernelGGL(transpose_k, dim3(128, 8, 4), dim3(32, 8), 0, stream, p2, p2t);
  hipLaunchKernelGGL(knn_k, dim3(512), dim3(256), 0, stream,
                     xyz1, xyz2, idx1, idx2, idx3, wgt);
  hipLaunchKernelGGL(interp_k, dim3(512), dim3(256), 0, stream, p2t, idx3, wgt, itp);
  hipLaunchKernelGGL(gemm1_k, dim3(1024, 4), dim3(256), 0, stream, p1, itp, w1, h1);
  hipLaunchKernelGGL((bnstats_k<0>), dim3(256), dim3(256), 0, stream, h1, g1, be1, a1, c1);
  hipLaunchKernelGGL(gemm2_k, dim3(1024, 2), dim3(256), 0, stream, h1, w2, a1, c1, out);
  hipLaunchKernelGGL((bnstats_k<1>), dim3(128), dim3(256), 0, stream, out, g2, be2, a2, c2);
  hipLaunchKernelGGL(bnapply_k, dim3(8192), dim3(256), 0, stream, out, a2, c2);
}